// Round 9
// baseline (107.345 us; speedup 1.0000x reference)
//
#include <hip/hip_runtime.h>

// lat [2048,2048] fp32 -> 131072 rows x D=32; centroids [1024,32] fp32.
// out = [lat * clamp(lf,1e-3,1e3)] ++ [1.25 * mean_{N,D}(min_k ||z-c_k||^2)]
#define D 32
#define K 1024
#define N_ROWS 131072
#define TOTAL_ELEMS 4194304
#define LOSS_SCALE (1.25f / 4194304.0f)
#define BIAS 192.0f   // score = ||c||^2 - 2 z.c + BIAS > 0 -> uint-comparable

typedef __attribute__((ext_vector_type(8))) short short8;   // 8 bf16
typedef __attribute__((ext_vector_type(4))) float f32x4;

__device__ __forceinline__ unsigned short f2bf(float f) {
  unsigned u = __builtin_bit_cast(unsigned, f);
  unsigned r = u + 0x7FFFu + ((u >> 16) & 1u);   // RNE
  return (unsigned short)(r >> 16);
}

// ---- prep: centbf = bf16(-2c); cnormb = ||c||^2 + BIAS; zero loss slot ----
__global__ __launch_bounds__(256) void prep_kernel(
    const float* __restrict__ cent, unsigned short* __restrict__ centbf,
    float* __restrict__ cnormb, float* __restrict__ loss_out) {
  int t = blockIdx.x * 256 + threadIdx.x;   // 0..32767
  centbf[t] = f2bf(-2.0f * cent[t]);
  if (t == 0) *loss_out = 0.0f;
  if (t < K) {
    const float* c = cent + t * D;
    float s0 = 0.f, s1 = 0.f, s2 = 0.f, s3 = 0.f;
#pragma unroll
    for (int d = 0; d < D; d += 4) {
      s0 = fmaf(c[d], c[d], s0);
      s1 = fmaf(c[d + 1], c[d + 1], s1);
      s2 = fmaf(c[d + 2], c[d + 2], s2);
      s3 = fmaf(c[d + 3], c[d + 3], s3);
    }
    cnormb[t] = (s0 + s1) + (s2 + s3) + BIAS;
  }
}

// ---- vq: 1-tile/wave MFMA argmin + fused scale-store + 4-phase LDS-B -----
// Wave = 16 rows (one A-tile); block = 4 waves = 64 rows; grid 2048 ->
// 8 blocks/CU (LDS 17.4 KB/block), 32 waves/CU = 100% occupancy cap.
// Derived from the r8 PASSING kernel by DELETING the a1/pk1 tile path and
// splitting LDS staging 2x32KB -> 4x16KB. Pack/butterfly/recompute logic
// unchanged (r3/r7/r8-verified).
__global__ __launch_bounds__(256) void vq_kernel(
    const float* __restrict__ lat, const float* __restrict__ cent,
    const unsigned short* __restrict__ centbf, const float* __restrict__ cnormb,
    const float* __restrict__ lf_ptr, float* __restrict__ out,
    float* __restrict__ loss_out) {
  __shared__ short8 sB8[1024];   // 16 KB: 256 centroids x 32 bf16 per phase
  __shared__ float sCn[256];     // 1 KB per phase
  __shared__ float wsum[4];
  const int tid = threadIdx.x;
  const int lane = tid & 63;
  const int wave = tid >> 6;
  const int quad = lane >> 4;
  const int col  = lane & 15;
  const int rowbase = blockIdx.x * 64 + wave * 16;

  // A-frag (lane holds A[row=col][k=quad*8+j]) + fused scale-store.
  float lf = fminf(fmaxf(lf_ptr[0], 0.001f), 1000.0f);
  short8 a0;
  {
    const float* p0 = lat + (size_t)(rowbase + col) * D + quad * 8;
    float4 u0 = ((const float4*)p0)[0], u1 = ((const float4*)p0)[1];
    a0[0] = (short)f2bf(u0.x); a0[1] = (short)f2bf(u0.y);
    a0[2] = (short)f2bf(u0.z); a0[3] = (short)f2bf(u0.w);
    a0[4] = (short)f2bf(u1.x); a0[5] = (short)f2bf(u1.y);
    a0[6] = (short)f2bf(u1.z); a0[7] = (short)f2bf(u1.w);
    float* o0 = out + (size_t)(rowbase + col) * D + quad * 8;
    float4 s00 = {u0.x * lf, u0.y * lf, u0.z * lf, u0.w * lf};
    float4 s01 = {u1.x * lf, u1.y * lf, u1.z * lf, u1.w * lf};
    ((float4*)o0)[0] = s00;
    ((float4*)o0)[1] = s01;
  }

  const f32x4 zero = {0.f, 0.f, 0.f, 0.f};
  unsigned pk0[4] = {0xFFFFFFFFu, 0xFFFFFFFFu, 0xFFFFFFFFu, 0xFFFFFFFFu};

  const short8* gB8 = (const short8*)centbf;   // 4096 short8 total

  for (int p = 0; p < 4; ++p) {
    __syncthreads();   // previous phase's readers done before overwrite
    // Stage 16 KB codebook slice + 1 KB cnorm slice (coalesced).
#pragma unroll
    for (int j = 0; j < 4; ++j)
      sB8[j * 256 + tid] = gB8[p * 1024 + j * 256 + tid];
    sCn[tid] = cnormb[p * 256 + tid];
    __syncthreads();

#pragma unroll 8
    for (int f = 0; f < 16; ++f) {
      // B-frag: lane holds B[k=quad*8+j][col] of centroid (p*256 + f*16+col)
      short8 b = sB8[f * 64 + col * 4 + quad];
      float cn = sCn[f * 16 + col];
      f32x4 d0 = __builtin_amdgcn_mfma_f32_16x16x32_bf16(a0, b, zero, 0, 0, 0);
      const unsigned idxv = (unsigned)(p * 256 + f * 16 + col);
#pragma unroll
      for (int r = 0; r < 4; ++r) {
        float s0 = d0[r] + cn;
        unsigned q0 = (__builtin_bit_cast(unsigned, s0) & 0xFFFFFC00u) | idxv;
        pk0[r] = pk0[r] < q0 ? pk0[r] : q0;
      }
    }
  }

  // Min across the 16 lanes of each quad-group (cols 0..15 of each row).
#pragma unroll
  for (int off = 1; off < 16; off <<= 1) {
#pragma unroll
    for (int r = 0; r < 4; ++r) {
      unsigned o0 = __shfl_xor(pk0[r], off);
      pk0[r] = pk0[r] < o0 ? pk0[r] : o0;
    }
  }

  // Exact fp32 recompute (r3-verified slicing, single tile): lane
  // (rsel=lane&3, q=(lane>>2)&3, quad) owns quarter q of row quad*4+rsel.
  // 64 lanes = 16 rows x 4 quarters, each exactly once.
  const int rsel = lane & 3;
  const int q = (lane >> 2) & 3;
  float s;
  {
    unsigned pv = pk0[rsel];
    int row = rowbase + quad * 4 + rsel;
    int ci = (int)(pv & 1023u);
    const float* zp = lat + (size_t)row * D + q * 8;
    const float* cp = cent + (size_t)ci * D + q * 8;
    float4 za = ((const float4*)zp)[0], zb = ((const float4*)zp)[1];
    float4 ca = ((const float4*)cp)[0], cb = ((const float4*)cp)[1];
    float f0 = za.x - ca.x, f1 = za.y - ca.y, f2 = za.z - ca.z, f3 = za.w - ca.w;
    float g0 = zb.x - cb.x, g1 = zb.y - cb.y, g2 = zb.z - cb.z, g3 = zb.w - cb.w;
    float m0 = fmaf(f0, f0, g0 * g0);
    float m1 = fmaf(f1, f1, g1 * g1);
    float m2 = fmaf(f2, f2, g2 * g2);
    float m3 = fmaf(f3, f3, g3 * g3);
    s = (m0 + m1) + (m2 + m3);
  }
  // Full 64-lane butterfly -> wave total (each row counted exactly once).
  s += __shfl_xor(s, 4);
  s += __shfl_xor(s, 8);
  s += __shfl_xor(s, 1);
  s += __shfl_xor(s, 2);
  s += __shfl_xor(s, 16);
  s += __shfl_xor(s, 32);

  if (lane == 0) wsum[wave] = s;
  __syncthreads();
  if (threadIdx.x == 0) {
    float blk = (wsum[0] + wsum[1]) + (wsum[2] + wsum[3]);
    atomicAdd(loss_out, blk * LOSS_SCALE);
  }
}

extern "C" void kernel_launch(void* const* d_in, const int* in_sizes, int n_in,
                              void* d_out, int out_size, void* d_ws, size_t ws_size,
                              hipStream_t stream) {
  const float* lat  = (const float*)d_in[0];
  const float* cent = (const float*)d_in[1];
  const float* lf   = (const float*)d_in[2];
  float* out = (float*)d_out;
  unsigned short* centbf = (unsigned short*)d_ws;                 // 64 KB
  float* cnormb = (float*)((char*)d_ws + K * D * sizeof(unsigned short));
  float* loss = out + TOTAL_ELEMS;

  prep_kernel<<<K * D / 256, 256, 0, stream>>>(cent, centbf, cnormb, loss);
  vq_kernel<<<N_ROWS / 64, 256, 0, stream>>>(lat, cent, centbf, cnormb, lf,
                                             out, loss);
}

// Round 10
// 97.680 us; speedup vs baseline: 1.0989x; 1.0989x over previous
//
#include <hip/hip_runtime.h>

// lat [2048,2048] fp32 -> 131072 rows x D=32; centroids [1024,32] fp32.
// out = [lat * clamp(lf,1e-3,1e3)] ++ [1.25 * mean_{N,D}(min_k ||z-c_k||^2)]
#define D 32
#define K 1024
#define N_ROWS 131072
#define TOTAL_ELEMS 4194304
#define LOSS_SCALE (1.25f / 4194304.0f)
#define BIAS 192.0f   // score = ||c||^2 - 2 z.c + BIAS > 0 -> uint-comparable

typedef __attribute__((ext_vector_type(8))) short short8;   // 8 bf16
typedef __attribute__((ext_vector_type(4))) float f32x4;

__device__ __forceinline__ unsigned short f2bf(float f) {
  unsigned u = __builtin_bit_cast(unsigned, f);
  unsigned r = u + 0x7FFFu + ((u >> 16) & 1u);   // RNE
  return (unsigned short)(r >> 16);
}

// ---- prep: centbf = bf16(-2c); cnormb = ||c||^2 + BIAS; zero loss slot ----
__global__ __launch_bounds__(256) void prep_kernel(
    const float* __restrict__ cent, unsigned short* __restrict__ centbf,
    float* __restrict__ cnormb, float* __restrict__ loss_out) {
  int t = blockIdx.x * 256 + threadIdx.x;   // 0..32767
  centbf[t] = f2bf(-2.0f * cent[t]);
  if (t == 0) *loss_out = 0.0f;
  if (t < K) {
    const float* c = cent + t * D;
    float s0 = 0.f, s1 = 0.f, s2 = 0.f, s3 = 0.f;
#pragma unroll
    for (int d = 0; d < D; d += 4) {
      s0 = fmaf(c[d], c[d], s0);
      s1 = fmaf(c[d + 1], c[d + 1], s1);
      s2 = fmaf(c[d + 2], c[d + 2], s2);
      s3 = fmaf(c[d + 3], c[d + 3], s3);
    }
    cnormb[t] = (s0 + s1) + (s2 + s3) + BIAS;
  }
}

// ---- vq: B-stationary persistent blocks -----------------------------------
// Grid 512 (2 blocks/CU); block stages the FULL codebook (64KB) + cn (4KB)
// in LDS once, then each wave runs the r8-VERIFIED 2-tile body twice
// (2 x 32 rows) with ZERO barriers in the main loops (LDS read-only).
// r9 lesson: phase-barrier lockstep was the 75% stall; staging traffic and
// barriers both drop 4x vs r8 here.
__global__ __launch_bounds__(256) void vq_kernel(
    const float* __restrict__ lat, const float* __restrict__ cent,
    const unsigned short* __restrict__ centbf, const float* __restrict__ cnormb,
    const float* __restrict__ lf_ptr, float* __restrict__ out,
    float* __restrict__ loss_out) {
  __shared__ short8 sB8[4096];   // 64 KB: 1024 centroids x 32 bf16
  __shared__ float sCn[1024];    // 4 KB
  __shared__ float wsum[4];
  const int tid = threadIdx.x;
  const int lane = tid & 63;
  const int wave = tid >> 6;
  const int quad = lane >> 4;
  const int col  = lane & 15;

  // One-time stage of the whole codebook + cnorm (coalesced).
  {
    const short8* gB8 = (const short8*)centbf;   // 4096 chunks
#pragma unroll
    for (int j = 0; j < 16; ++j) sB8[j * 256 + tid] = gB8[j * 256 + tid];
#pragma unroll
    for (int j = 0; j < 4; ++j) sCn[j * 256 + tid] = cnormb[j * 256 + tid];
  }

  // Prologue: A-frags for BOTH row-tile-pair iterations + fused scale-store.
  // (8 outstanding dwordx4 loads/lane stream the HBM read.)
  float lf = fminf(fmaxf(lf_ptr[0], 0.001f), 1000.0f);
  short8 a[2][2];
#pragma unroll
  for (int it = 0; it < 2; ++it) {
    const int rowbase = blockIdx.x * 256 + it * 128 + wave * 32;
    const float* p0 = lat + (size_t)(rowbase + col) * D + quad * 8;
    const float* p1 = p0 + 16 * D;
    float4 u0 = ((const float4*)p0)[0], u1 = ((const float4*)p0)[1];
    float4 w0 = ((const float4*)p1)[0], w1 = ((const float4*)p1)[1];
    a[it][0][0] = (short)f2bf(u0.x); a[it][0][1] = (short)f2bf(u0.y);
    a[it][0][2] = (short)f2bf(u0.z); a[it][0][3] = (short)f2bf(u0.w);
    a[it][0][4] = (short)f2bf(u1.x); a[it][0][5] = (short)f2bf(u1.y);
    a[it][0][6] = (short)f2bf(u1.z); a[it][0][7] = (short)f2bf(u1.w);
    a[it][1][0] = (short)f2bf(w0.x); a[it][1][1] = (short)f2bf(w0.y);
    a[it][1][2] = (short)f2bf(w0.z); a[it][1][3] = (short)f2bf(w0.w);
    a[it][1][4] = (short)f2bf(w1.x); a[it][1][5] = (short)f2bf(w1.y);
    a[it][1][6] = (short)f2bf(w1.z); a[it][1][7] = (short)f2bf(w1.w);
    float* o0 = out + (size_t)(rowbase + col) * D + quad * 8;
    float* o1 = o0 + 16 * D;
    float4 s00 = {u0.x * lf, u0.y * lf, u0.z * lf, u0.w * lf};
    float4 s01 = {u1.x * lf, u1.y * lf, u1.z * lf, u1.w * lf};
    float4 s10 = {w0.x * lf, w0.y * lf, w0.z * lf, w0.w * lf};
    float4 s11 = {w1.x * lf, w1.y * lf, w1.z * lf, w1.w * lf};
    ((float4*)o0)[0] = s00;
    ((float4*)o0)[1] = s01;
    ((float4*)o1)[0] = s10;
    ((float4*)o1)[1] = s11;
  }
  __syncthreads();   // the ONLY barrier before the reduction

  const f32x4 zero = {0.f, 0.f, 0.f, 0.f};
  float sacc = 0.f;

#pragma unroll
  for (int it = 0; it < 2; ++it) {
    const int rowbase = blockIdx.x * 256 + it * 128 + wave * 32;
    const short8 a0 = a[it][0], a1 = a[it][1];
    unsigned pk0[4] = {0xFFFFFFFFu, 0xFFFFFFFFu, 0xFFFFFFFFu, 0xFFFFFFFFu};
    unsigned pk1[4] = {0xFFFFFFFFu, 0xFFFFFFFFu, 0xFFFFFFFFu, 0xFFFFFFFFu};

#pragma unroll 8
    for (int f = 0; f < 64; ++f) {
      // B-frag: lane holds B[k=quad*8+j][col] of centroid f*16+col.
      short8 b = sB8[f * 64 + col * 4 + quad];
      float cn = sCn[f * 16 + col];
      f32x4 d0 = __builtin_amdgcn_mfma_f32_16x16x32_bf16(a0, b, zero, 0, 0, 0);
      f32x4 d1 = __builtin_amdgcn_mfma_f32_16x16x32_bf16(a1, b, zero, 0, 0, 0);
      const unsigned idxv = (unsigned)(f * 16 + col);
#pragma unroll
      for (int r = 0; r < 4; ++r) {
        float s0 = d0[r] + cn;
        unsigned q0 = (__builtin_bit_cast(unsigned, s0) & 0xFFFFFC00u) | idxv;
        pk0[r] = pk0[r] < q0 ? pk0[r] : q0;
        float s1 = d1[r] + cn;
        unsigned q1 = (__builtin_bit_cast(unsigned, s1) & 0xFFFFFC00u) | idxv;
        pk1[r] = pk1[r] < q1 ? pk1[r] : q1;
      }
    }

    // Min across the 16 lanes of each quad-group.
#pragma unroll
    for (int off = 1; off < 16; off <<= 1) {
#pragma unroll
      for (int r = 0; r < 4; ++r) {
        unsigned o0 = __shfl_xor(pk0[r], off);
        pk0[r] = pk0[r] < o0 ? pk0[r] : o0;
        unsigned o1 = __shfl_xor(pk1[r], off);
        pk1[r] = pk1[r] < o1 ? pk1[r] : o1;
      }
    }

    // Exact fp32 recompute of d_min for winners (r3/r8-verified slicing).
    const int rsel = lane & 3;
    const int q = (lane >> 2) & 3;
    float s = 0.f;
#pragma unroll
    for (int t = 0; t < 2; ++t) {
      unsigned pk = (t == 0) ? pk0[rsel] : pk1[rsel];
      int row = rowbase + t * 16 + quad * 4 + rsel;
      int ci = (int)(pk & 1023u);
      const float* zp = lat + (size_t)row * D + q * 8;
      const float* cp = cent + (size_t)ci * D + q * 8;
      float4 za = ((const float4*)zp)[0], zb = ((const float4*)zp)[1];
      float4 ca = ((const float4*)cp)[0], cb = ((const float4*)cp)[1];
      float f0 = za.x - ca.x, f1 = za.y - ca.y;
      float f2 = za.z - ca.z, f3 = za.w - ca.w;
      float g0 = zb.x - cb.x, g1 = zb.y - cb.y;
      float g2 = zb.z - cb.z, g3 = zb.w - cb.w;
      float m0 = fmaf(f0, f0, g0 * g0);
      float m1 = fmaf(f1, f1, g1 * g1);
      float m2 = fmaf(f2, f2, g2 * g2);
      float m3 = fmaf(f3, f3, g3 * g3);
      s += (m0 + m1) + (m2 + m3);
    }
    // Full 64-lane butterfly: all-lane sum counts each of the 32 rows once.
    s += __shfl_xor(s, 4);
    s += __shfl_xor(s, 8);
    s += __shfl_xor(s, 1);
    s += __shfl_xor(s, 2);
    s += __shfl_xor(s, 16);
    s += __shfl_xor(s, 32);
    sacc += s;
  }

  if (lane == 0) wsum[wave] = sacc;
  __syncthreads();
  if (threadIdx.x == 0) {
    float blk = (wsum[0] + wsum[1]) + (wsum[2] + wsum[3]);
    atomicAdd(loss_out, blk * LOSS_SCALE);
  }
}

extern "C" void kernel_launch(void* const* d_in, const int* in_sizes, int n_in,
                              void* d_out, int out_size, void* d_ws, size_t ws_size,
                              hipStream_t stream) {
  const float* lat  = (const float*)d_in[0];
  const float* cent = (const float*)d_in[1];
  const float* lf   = (const float*)d_in[2];
  float* out = (float*)d_out;
  unsigned short* centbf = (unsigned short*)d_ws;                 // 64 KB
  float* cnormb = (float*)((char*)d_ws + K * D * sizeof(unsigned short));
  float* loss = out + TOTAL_ELEMS;

  prep_kernel<<<K * D / 256, 256, 0, stream>>>(cent, centbf, cnormb, loss);
  vq_kernel<<<N_ROWS / 256, 256, 0, stream>>>(lat, cent, centbf, cnormb, lf,
                                              out, loss);
}